// Round 7
// baseline (619.682 us; speedup 1.0000x reference)
//
#include <hip/hip_runtime.h>
#include <math.h>

#define B_ 8
#define L_ 2048
#define DM 6
#define ED 48
#define NS 32
#define DCONV 16
#define NLAYERS 4
#define NCLASSES 4
#define EPS 1e-5f

#define CH 32              // chunks per sequence
#define CL 64              // steps per chunk
#define HALO (DCONV - 1)   // 15
#define TP (CL + HALO)     // 79 positions incl. halo

// Workspace layouts:
//   y        : [b][e][l]
//   hA/hB    : [b][d][l]  residual ping-pong
//   gA/gH    : [chunk][e][n] chunk summaries (per layer, reused)
//   flags    : [layer][chunk] lookback flags

__global__ void k_zero_flags(int* flags)
{
    int t = threadIdx.x;
    if (t < NLAYERS * CH) flags[t] = 0;
}

__global__ void __launch_bounds__(256) k_layer(
    const float* __restrict__ x,      // [b][l][dm] raw input (layer 0)
    const float* __restrict__ yprev,  // [b][e][l] gated y of prev layer
    const float* __restrict__ outw,   // (6,48) prev layer out_proj
    const float* __restrict__ hin,    // [b][dm][l] residual in (layer>0)
    float* __restrict__ hout,         // [b][dm][l] residual out (layer<3)
    const float* __restrict__ ipw,    // (96,6)
    const float* __restrict__ nw,     // (6)
    const float* __restrict__ cw,     // (48,16)
    const float* __restrict__ cb,     // (48)
    const float* __restrict__ xpw,    // (65,48)
    const float* __restrict__ dtw,    // (48)
    const float* __restrict__ dtb,    // (48)
    const float* __restrict__ A_log,  // (48,32)
    const float* __restrict__ Dp,     // (48)
    const float* __restrict__ fcw,    // (4,48)
    const float* __restrict__ fcb,    // (4)
    float* __restrict__ y,            // [b][e][l]
    float* __restrict__ gA, float* __restrict__ gH,
    int* __restrict__ flags,
    float* __restrict__ out,
    int layer)
{
    __shared__ __attribute__((aligned(16))) float sh[DM][TP + 1];
    __shared__ float srn[TP + 1];
    __shared__ __attribute__((aligned(16))) float sxin[ED][TP + 1];
    __shared__ __attribute__((aligned(16))) float sxc[ED][CL];
    __shared__ __attribute__((aligned(16))) float sdel[ED][CL];
    __shared__ __attribute__((aligned(16))) float sz[ED][CL];
    __shared__ float sB[CL][NS + 1];   // +1 pad: conflict-free write & read
    __shared__ float sC[CL][NS + 1];
    __shared__ float sdr[CL];
    __shared__ float sy[ED];           // last-token stash for classifier

    int b     = blockIdx.x >> 5;       // 32 chunks per batch
    int chunk = blockIdx.x & (CH - 1);
    int l0    = chunk * CL;
    int tid   = threadIdx.x;

    // ---- Phase A1: residual h for TP positions (halo recomputed) ----
    for (int i = tid; i < DM * TP; i += 256) {
        int d = i / TP, p = i - d * TP;
        int l = l0 - HALO + p;
        float hv = 0.f;
        if (l >= 0) {
            if (layer == 0) {
                hv = x[((size_t)b * L_ + l) * DM + d];
            } else {
                hv = hin[((size_t)b * DM + d) * L_ + l];
                const float* yp = yprev + (size_t)b * ED * L_ + l;
                const float* wp = outw + d * ED;
                float acc = 0.f;
#pragma unroll
                for (int e = 0; e < ED; ++e) acc += yp[(size_t)e * L_] * wp[e];
                hv += acc;
            }
            if (p >= HALO && layer < NLAYERS - 1)
                hout[((size_t)b * DM + d) * L_ + l] = hv;
        }
        sh[d][p] = hv;
    }
    __syncthreads();

    // ---- Phase A2: rms scale ----
    if (tid < TP) {
        float ss = 0.f;
#pragma unroll
        for (int d = 0; d < DM; ++d) ss += sh[d][tid] * sh[d][tid];
        srn[tid] = rsqrtf(ss * (1.f / DM) + EPS);
    }
    __syncthreads();

    // ---- Phase A3: in_proj -> xin (TP pos, LDS) and z (CL pos, LDS) ----
    for (int i = tid; i < ED * TP; i += 256) {
        int e = i / TP, p = i - e * TP;
        const float* wp = ipw + e * DM;
        float acc = 0.f;
#pragma unroll
        for (int d = 0; d < DM; ++d) acc += sh[d][p] * nw[d] * wp[d];
        sxin[e][p] = acc * srn[p];
    }
    for (int i = tid; i < ED * CL; i += 256) {
        int e = i >> 6, po = i & 63;
        int p = po + HALO;
        const float* wp = ipw + (ED + e) * DM;
        float acc = 0.f;
#pragma unroll
        for (int d = 0; d < DM; ++d) acc += sh[d][p] * nw[d] * wp[d];
        sz[e][po] = acc * srn[p];
    }
    __syncthreads();

    // ---- Phase A4: conv + SiLU ----
    for (int i = tid; i < ED * CL; i += 256) {
        int e = i >> 6, po = i & 63;
        const float* wp = cw + e * DCONV;
        float acc = cb[e];
#pragma unroll
        for (int k = 0; k < DCONV; ++k) acc += sxin[e][po + k] * wp[k];
        sxc[e][po] = acc / (1.f + __expf(-acc));
    }
    __syncthreads();

    // ---- Phase A5: x_proj (65 rows) -> sB, sC, sdr ----
    {
        int og = tid >> 5, li0 = tid & 31;
        int isB = og < 4;
        int nb = (og & 3) * 8;
        int rowBase = isB ? (1 + nb) : (1 + NS + nb);
        const float* wr = xpw + rowBase * ED;
#pragma unroll
        for (int half = 0; half < 2; ++half) {
            int li = li0 + 32 * half;
            float a0=0,a1=0,a2=0,a3=0,a4=0,a5=0,a6=0,a7=0, dr=0;
#pragma unroll 4
            for (int e = 0; e < ED; ++e) {
                float xv = sxc[e][li];
                a0 += xv * wr[0*ED+e]; a1 += xv * wr[1*ED+e];
                a2 += xv * wr[2*ED+e]; a3 += xv * wr[3*ED+e];
                a4 += xv * wr[4*ED+e]; a5 += xv * wr[5*ED+e];
                a6 += xv * wr[6*ED+e]; a7 += xv * wr[7*ED+e];
                dr += xv * xpw[e];
            }
            float* dst = isB ? &sB[li][nb] : &sC[li][nb];
            dst[0]=a0; dst[1]=a1; dst[2]=a2; dst[3]=a3;
            dst[4]=a4; dst[5]=a5; dst[6]=a6; dst[7]=a7;
            if (og == 0) sdr[li] = dr;
        }
    }
    __syncthreads();

    // ---- Phase A6: delta = softplus(dr*dtw + dtb) ----
    for (int i = tid; i < ED * CL; i += 256) {
        int e = i >> 6, po = i & 63;
        float s = sdr[po] * dtw[e] + dtb[e];
        sdel[e][po] = fmaxf(s, 0.f) + log1pf(__expf(-fabsf(s)));
    }
    __syncthreads();

    // ---- Phase B: local chunk scan, 6 (e,n) chains per thread ----
    int g2 = tid >> 5;          // 8 groups of 32 lanes
    int n  = tid & 31;
    int e0 = g2 * 6;
    float Aj[6], hb[6], sd[6];
#pragma unroll
    for (int j = 0; j < 6; ++j) {
        Aj[j] = -__expf(A_log[(e0 + j) * NS + n]);
        hb[j] = 0.f; sd[j] = 0.f;
    }
    for (int l = 0; l < CL; ++l) {
        float bb = sB[l][n];
#pragma unroll
        for (int j = 0; j < 6; ++j) {
            float dv = sdel[e0 + j][l];
            float xv = sxc[e0 + j][l];
            hb[j] = __expf(dv * Aj[j]) * hb[j] + (dv * xv) * bb;
            sd[j] += dv;
        }
    }
#pragma unroll
    for (int j = 0; j < 6; ++j) {
        size_t idx = ((size_t)chunk * ED + e0 + j) * NS + n;
        gA[idx] = __expf(Aj[j] * sd[j]);
        gH[idx] = hb[j];
    }
    // publish (release)
    __threadfence();
    __syncthreads();
    int* flagRow = flags + layer * CH;
    if (tid == 0)
        __hip_atomic_store(&flagRow[chunk], 1, __ATOMIC_RELEASE,
                           __HIP_MEMORY_SCOPE_AGENT);

    // ---- Phase C: lookback fold of predecessor summaries ----
    float hp[6];
#pragma unroll
    for (int j = 0; j < 6; ++j) hp[j] = 0.f;
    if (chunk > 0) {
        if (tid < chunk) {
            while (__hip_atomic_load(&flagRow[tid], __ATOMIC_ACQUIRE,
                                     __HIP_MEMORY_SCOPE_AGENT) == 0) {
                __builtin_amdgcn_s_sleep(1);
            }
        }
        __syncthreads();
        __threadfence();
        for (int c = 0; c < chunk; ++c) {
#pragma unroll
            for (int j = 0; j < 6; ++j) {
                size_t idx = ((size_t)c * ED + e0 + j) * NS + n;
                hp[j] = gA[idx] * hp[j] + gH[idx];
            }
        }
    }

    // ---- Phase D: final scan + reduce + gate + y write ----
    bool doD = (layer < NLAYERS - 1) || (chunk == CH - 1);
    if (doD) {
        int s0 = n & 1, s1 = n & 2;
#pragma unroll 1
        for (int j = 0; j < 6; ++j) {
            int e = e0 + j;
            float Dv = Dp[e];
            float A = Aj[j];
            float h = hp[j];
            const float4* dRow = (const float4*)&sdel[e][0];
            const float4* xRow = (const float4*)&sxc[e][0];
            float* yRow = y + ((size_t)b * ED + e) * L_ + l0;
            for (int q = 0; q < CL / 4; ++q) {
                float4 d4 = dRow[q];
                float4 x4 = xRow[q];
                float bb0 = sB[4*q+0][n], bb1 = sB[4*q+1][n];
                float bb2 = sB[4*q+2][n], bb3 = sB[4*q+3][n];
                float cc0 = sC[4*q+0][n], cc1 = sC[4*q+1][n];
                float cc2 = sC[4*q+2][n], cc3 = sC[4*q+3][n];
                h = __expf(d4.x*A)*h + (d4.x*x4.x)*bb0;  float p0 = h*cc0;
                h = __expf(d4.y*A)*h + (d4.y*x4.y)*bb1;  float p1 = h*cc1;
                h = __expf(d4.z*A)*h + (d4.z*x4.z)*bb2;  float p2 = h*cc2;
                h = __expf(d4.w*A)*h + (d4.w*x4.w)*bb3;  float p3 = h*cc3;
                // batched butterfly: lane%4==k ends with sum over 32 lanes of p_k
                float u  = s0 ? p1 : p0;
                float us = s0 ? p0 : p1;
                u += __shfl_xor(us, 1, 32);
                float v  = s0 ? p3 : p2;
                float vs = s0 ? p2 : p3;
                v += __shfl_xor(vs, 1, 32);
                float wv  = s1 ? v : u;
                float wvs = s1 ? u : v;
                wv += __shfl_xor(wvs, 2, 32);
                wv += __shfl_xor(wv, 4, 32);
                wv += __shfl_xor(wv, 8, 32);
                wv += __shfl_xor(wv, 16, 32);
                if (n < 4) {
                    float xs = (n == 0) ? x4.x : (n == 1) ? x4.y
                             : (n == 2) ? x4.z : x4.w;
                    float yr = wv + Dv * xs;
                    float zv = sz[e][4*q + n];
                    float yo = yr * (zv / (1.f + __expf(-zv)));
                    if (layer < NLAYERS - 1) yRow[4*q + n] = yo;
                    else if (q == CL/4 - 1 && n == 3) sy[e] = yo;
                }
            }
        }
    }

    // ---- classifier fused into last layer, last chunk ----
    if (layer == NLAYERS - 1 && chunk == CH - 1) {
        __syncthreads();
        if (tid < NCLASSES) {
            float acc = fcb[tid];
#pragma unroll
            for (int e = 0; e < ED; ++e) acc += sy[e] * fcw[tid * ED + e];
            out[b * NCLASSES + tid] = acc;
        }
    }
}

// ---------------------------------------------------------------------------
extern "C" void kernel_launch(void* const* d_in, const int* in_sizes, int n_in,
                              void* d_out, int out_size, void* d_ws, size_t ws_size,
                              hipStream_t stream)
{
    const float* x          = (const float*)d_in[0];
    const float* in_proj_w  = (const float*)d_in[1];
    const float* conv_w     = (const float*)d_in[2];
    const float* conv_b     = (const float*)d_in[3];
    const float* x_proj_w   = (const float*)d_in[4];
    const float* dt_proj_w  = (const float*)d_in[5];
    const float* dt_proj_b  = (const float*)d_in[6];
    const float* A_log      = (const float*)d_in[7];
    const float* Dp         = (const float*)d_in[8];
    const float* out_proj_w = (const float*)d_in[9];
    const float* norm_w     = (const float*)d_in[10];
    const float* fc_w       = (const float*)d_in[11];
    const float* fc_b       = (const float*)d_in[12];

    float* ws = (float*)d_ws;
    float* y  = ws;                          // B*48*L = 786432
    float* hA = y  + (size_t)B_ * ED * L_;   // B*6*L  = 98304
    float* hB = hA + (size_t)B_ * DM * L_;   // 98304
    float* gA = hB + (size_t)B_ * DM * L_;   // CH*ED*NS = 49152
    float* gH = gA + (size_t)CH * ED * NS;   // 49152
    int* flags = (int*)(gH + (size_t)CH * ED * NS);  // 128 ints

    k_zero_flags<<<1, 128, 0, stream>>>(flags);

    for (int i = 0; i < NLAYERS; ++i) {
        float* hout      = (i & 1) ? hB : hA;
        const float* hin = (i & 1) ? hA : hB;
        const float* ow  = (i == 0) ? out_proj_w
                                    : out_proj_w + (size_t)(i - 1) * DM * ED;
        k_layer<<<B_ * CH, 256, 0, stream>>>(
            x, y, ow, hin, hout,
            in_proj_w + (size_t)i * 96 * DM, norm_w + (size_t)i * DM,
            conv_w + (size_t)i * ED * DCONV, conv_b + (size_t)i * ED,
            x_proj_w + (size_t)i * 65 * ED,
            dt_proj_w + (size_t)i * ED, dt_proj_b + (size_t)i * ED,
            A_log + (size_t)i * ED * NS, Dp + (size_t)i * ED,
            fc_w, fc_b,
            y, gA, gH, flags, (float*)d_out, i);
    }
}

// Round 8
// 383.396 us; speedup vs baseline: 1.6163x; 1.6163x over previous
//
#include <hip/hip_runtime.h>
#include <math.h>

#define B_ 8
#define L_ 2048
#define DM 6
#define ED 48
#define NS 32
#define DCONV 16
#define NLAYERS 4
#define NCLASSES 4
#define EPS 1e-5f

#define CH 64              // chunks per sequence
#define CL 32              // steps per chunk (== fused tile width)
#define HALO (DCONV - 1)   // 15
#define TP (CL + HALO)     // 47 positions incl. halo

// Layouts:
//   z, xc, delta, y : [b][e][l]   (l contiguous)
//   Bm, Cm          : [b][l][n]   (n contiguous)
//   gA, gH          : [b*ED+e][chunk][n]  chunk summaries

// ---------------------------------------------------------------------------
// Fused pre-scan + local-chunk-scan kernel. Block = (b, 32-pos chunk).
// Residual update, RMSNorm, in_proj, conv+SiLU, x_proj, delta — all in LDS —
// then each 32-lane group scans 6 channels x 32 steps from LDS and publishes
// the chunk summary (telescoped exp(A*sum d), local h end) for k_scan.
__global__ void __launch_bounds__(256) k_fused_pre(
    const float* __restrict__ x,      // [b][l][dm] raw input (layer 0)
    const float* __restrict__ yprev,  // [b][e][l] gated y of prev layer
    const float* __restrict__ outw,   // (6,48) prev layer out_proj
    const float* __restrict__ hin,    // [b][dm][l] residual in (layer>0)
    float* __restrict__ hout,         // [b][dm][l] residual out (layer<3)
    const float* __restrict__ ipw,    // (96,6)
    const float* __restrict__ nw,     // (6)
    const float* __restrict__ cw,     // (48,16)
    const float* __restrict__ cb,     // (48)
    const float* __restrict__ xpw,    // (65,48)
    const float* __restrict__ dtw,    // (48)
    const float* __restrict__ dtb,    // (48)
    const float* __restrict__ A_log,  // (48,32)
    float* __restrict__ z,
    float* __restrict__ xcg,
    float* __restrict__ delta,
    float* __restrict__ Bm, float* __restrict__ Cm,
    float* __restrict__ gA, float* __restrict__ gH,
    int layer)
{
    __shared__ float sh[DM][TP + 1];
    __shared__ float srn[TP + 1];
    __shared__ float sxin[ED][TP + 1];
    __shared__ float sxc[ED][CL + 1];
    __shared__ float sdel[ED][CL];
    __shared__ float sB[CL][NS + 1];
    __shared__ float sdr[CL];

    int b     = blockIdx.x >> 6;         // 64 chunks per batch
    int chunk = blockIdx.x & (CH - 1);
    int l0    = chunk * CL;
    int tid   = threadIdx.x;

    // ---- A1: residual h for TP positions (halo recomputed) ----
    for (int i = tid; i < DM * TP; i += 256) {
        int d = i / TP, p = i - d * TP;
        int l = l0 - HALO + p;
        float hv = 0.f;
        if (l >= 0) {
            if (layer == 0) {
                hv = x[((size_t)b * L_ + l) * DM + d];
            } else {
                hv = hin[((size_t)b * DM + d) * L_ + l];
                const float* yp = yprev + (size_t)b * ED * L_ + l;
                const float* wp = outw + d * ED;
                float acc = 0.f;
#pragma unroll
                for (int e = 0; e < ED; ++e) acc += yp[(size_t)e * L_] * wp[e];
                hv += acc;
            }
            if (p >= HALO && layer < NLAYERS - 1)
                hout[((size_t)b * DM + d) * L_ + l] = hv;
        }
        sh[d][p] = hv;
    }
    __syncthreads();

    // ---- A2: rms scale ----
    if (tid < TP) {
        float ss = 0.f;
#pragma unroll
        for (int d = 0; d < DM; ++d) ss += sh[d][tid] * sh[d][tid];
        srn[tid] = rsqrtf(ss * (1.f / DM) + EPS);
    }
    __syncthreads();

    // ---- A3: in_proj -> xin (TP pos, LDS) and z (CL pos, global) ----
    for (int i = tid; i < ED * TP; i += 256) {
        int e = i / TP, p = i - e * TP;
        const float* wp = ipw + e * DM;
        float acc = 0.f;
#pragma unroll
        for (int d = 0; d < DM; ++d) acc += sh[d][p] * nw[d] * wp[d];
        sxin[e][p] = acc * srn[p];
    }
    for (int i = tid; i < ED * CL; i += 256) {
        int e = i >> 5, po = i & 31;
        int p = po + HALO;
        const float* wp = ipw + (ED + e) * DM;
        float acc = 0.f;
#pragma unroll
        for (int d = 0; d < DM; ++d) acc += sh[d][p] * nw[d] * wp[d];
        z[((size_t)b * ED + e) * L_ + l0 + po] = acc * srn[p];
    }
    __syncthreads();

    // ---- A4: conv + SiLU ----
    for (int i = tid; i < ED * CL; i += 256) {
        int e = i >> 5, po = i & 31;
        const float* wp = cw + e * DCONV;
        float acc = cb[e];
#pragma unroll
        for (int k = 0; k < DCONV; ++k) acc += sxin[e][po + k] * wp[k];
        float v = acc / (1.f + __expf(-acc));
        sxc[e][po] = v;
        xcg[((size_t)b * ED + e) * L_ + l0 + po] = v;
    }
    __syncthreads();

    // ---- A5: x_proj (65 rows) -> Bm/Cm global, sB LDS, sdr ----
    {
        int og = tid >> 5, li = tid & 31;
        int isB = og < 4;
        int nb = (og & 3) * 8;
        int rowBase = isB ? (1 + nb) : (1 + NS + nb);
        const float* wr = xpw + rowBase * ED;
        float a0=0,a1=0,a2=0,a3=0,a4=0,a5=0,a6=0,a7=0, dr=0;
#pragma unroll 4
        for (int e = 0; e < ED; ++e) {
            float xv = sxc[e][li];
            a0 += xv * wr[0*ED+e]; a1 += xv * wr[1*ED+e];
            a2 += xv * wr[2*ED+e]; a3 += xv * wr[3*ED+e];
            a4 += xv * wr[4*ED+e]; a5 += xv * wr[5*ED+e];
            a6 += xv * wr[6*ED+e]; a7 += xv * wr[7*ED+e];
            dr += xv * xpw[e];
        }
        float* outp = (isB ? Bm : Cm) + ((size_t)(b * L_ + l0 + li)) * NS + nb;
        ((float4*)outp)[0] = make_float4(a0, a1, a2, a3);
        ((float4*)outp)[1] = make_float4(a4, a5, a6, a7);
        if (isB) {
            float* dst = &sB[li][nb];
            dst[0]=a0; dst[1]=a1; dst[2]=a2; dst[3]=a3;
            dst[4]=a4; dst[5]=a5; dst[6]=a6; dst[7]=a7;
        }
        if (og == 0) sdr[li] = dr;
    }
    __syncthreads();

    // ---- A6: delta = softplus(dr*dtw + dtb) -> global + LDS ----
    for (int i = tid; i < ED * CL; i += 256) {
        int e = i >> 5, po = i & 31;
        float s = sdr[po] * dtw[e] + dtb[e];
        float dv = fmaxf(s, 0.f) + log1pf(__expf(-fabsf(s)));
        sdel[e][po] = dv;
        delta[((size_t)b * ED + e) * L_ + l0 + po] = dv;
    }
    __syncthreads();

    // ---- B: local chunk scan from LDS, 6 chains per thread ----
    {
        int g2 = tid >> 5;
        int n  = tid & 31;
        int e0 = g2 * 6;
        float Aj[6], hb[6], sd[6];
#pragma unroll
        for (int j = 0; j < 6; ++j) {
            Aj[j] = -__expf(A_log[(e0 + j) * NS + n]);
            hb[j] = 0.f; sd[j] = 0.f;
        }
        for (int l = 0; l < CL; ++l) {
            float bb = sB[l][n];
#pragma unroll
            for (int j = 0; j < 6; ++j) {
                float dv = sdel[e0 + j][l];
                float xv = sxc[e0 + j][l];
                hb[j] = __expf(dv * Aj[j]) * hb[j] + (dv * xv) * bb;
                sd[j] += dv;
            }
        }
#pragma unroll
        for (int j = 0; j < 6; ++j) {
            size_t idx = ((size_t)(b * ED + e0 + j) * CH + chunk) * NS + n;
            gA[idx] = __expf(Aj[j] * sd[j]);
            gH[idx] = hb[j];
        }
    }
}

// ---------------------------------------------------------------------------
// Scan pass 2: thread = (b,e,n,chunk). Folds predecessor chunk summaries
// (inline exclusive prefix), rescans its 32 steps, butterfly-reduces over n,
// gates with SiLU(z), writes y. Last layer: only chunk CH-1 runs.
__global__ void __launch_bounds__(256) k_scan(
    const float* __restrict__ delta, const float* __restrict__ xc,
    const float* __restrict__ Bm, const float* __restrict__ Cm,
    const float* __restrict__ z,
    const float* __restrict__ A_log,  // (48,32)
    const float* __restrict__ Dp,     // (48)
    const float* __restrict__ gA, const float* __restrict__ gH,
    float* __restrict__ y,
    int lastLayer)
{
    int t = blockIdx.x * blockDim.x + threadIdx.x;
    int n = t & 31;
    int g = t >> 5;
    if (g >= B_ * ED * CH) return;
    int chunk = g & (CH - 1);
    int be    = g >> 6;               // b*ED + e
    if (lastLayer && chunk != CH - 1) return;
    int e = be % ED;
    int b = be / ED;
    float A  = -__expf(A_log[e * NS + n]);
    float Dv = Dp[e];

    // inline exclusive prefix over earlier chunk summaries
    float h = 0.f;
    {
        size_t base = (size_t)be * CH;
        for (int c = 0; c < chunk; ++c) {
            size_t idx = (base + c) * NS + n;
            h = gA[idx] * h + gH[idx];
        }
    }

    size_t eRow = (size_t)be * L_ + chunk * CL;
    size_t nRow = ((size_t)b * L_ + chunk * CL) * NS + n;
    const float4* dRow = (const float4*)(delta + eRow);
    const float4* xRow = (const float4*)(xc + eRow);
    const float* bBase = Bm + nRow;
    const float* cBase = Cm + nRow;
    const float* zRow  = z + eRow;
    float*       yRow  = y + eRow;
    int s0 = n & 1, s1 = n & 2;
    for (int q = 0; q < CL / 4; ++q) {
        float4 d4 = dRow[q];
        float4 x4 = xRow[q];
        float bb0 = bBase[(4 * q + 0) * NS];
        float bb1 = bBase[(4 * q + 1) * NS];
        float bb2 = bBase[(4 * q + 2) * NS];
        float bb3 = bBase[(4 * q + 3) * NS];
        float cc0 = cBase[(4 * q + 0) * NS];
        float cc1 = cBase[(4 * q + 1) * NS];
        float cc2 = cBase[(4 * q + 2) * NS];
        float cc3 = cBase[(4 * q + 3) * NS];
        h = __expf(d4.x*A)*h + (d4.x*x4.x)*bb0;  float p0 = h*cc0;
        h = __expf(d4.y*A)*h + (d4.y*x4.y)*bb1;  float p1 = h*cc1;
        h = __expf(d4.z*A)*h + (d4.z*x4.z)*bb2;  float p2 = h*cc2;
        h = __expf(d4.w*A)*h + (d4.w*x4.w)*bb3;  float p3 = h*cc3;
        // batched butterfly: lane%4==k ends with sum over 32 lanes of p_k
        float u  = s0 ? p1 : p0;
        float us = s0 ? p0 : p1;
        u += __shfl_xor(us, 1, 32);
        float v  = s0 ? p3 : p2;
        float vs = s0 ? p2 : p3;
        v += __shfl_xor(vs, 1, 32);
        float wv  = s1 ? v : u;
        float wvs = s1 ? u : v;
        wv += __shfl_xor(wvs, 2, 32);
        wv += __shfl_xor(wv, 4, 32);
        wv += __shfl_xor(wv, 8, 32);
        wv += __shfl_xor(wv, 16, 32);
        if (n < 4) {
            float xs = (n == 0) ? x4.x : (n == 1) ? x4.y
                     : (n == 2) ? x4.z : x4.w;
            float yr = wv + Dv * xs;
            float zv = zRow[4*q + n];
            yRow[4*q + n] = yr * (zv / (1.f + __expf(-zv)));
        }
    }
}

// ---------------------------------------------------------------------------
// Classifier on last token (y is already gated).
__global__ void k_cls(const float* __restrict__ y,
                      const float* __restrict__ fcw,  // (4,48)
                      const float* __restrict__ fcb,  // (4)
                      float* __restrict__ out)
{
    int t = threadIdx.x;
    if (t >= B_ * NCLASSES) return;
    int b = t / NCLASSES;
    int c = t - b * NCLASSES;
    const float* yp = y + (size_t)b * ED * L_ + (L_ - 1);
    const float* wp = fcw + c * ED;
    float acc = fcb[c];
#pragma unroll
    for (int e = 0; e < ED; ++e) acc += yp[(size_t)e * L_] * wp[e];
    out[t] = acc;
}

// ---------------------------------------------------------------------------
extern "C" void kernel_launch(void* const* d_in, const int* in_sizes, int n_in,
                              void* d_out, int out_size, void* d_ws, size_t ws_size,
                              hipStream_t stream)
{
    const float* x          = (const float*)d_in[0];
    const float* in_proj_w  = (const float*)d_in[1];
    const float* conv_w     = (const float*)d_in[2];
    const float* conv_b     = (const float*)d_in[3];
    const float* x_proj_w   = (const float*)d_in[4];
    const float* dt_proj_w  = (const float*)d_in[5];
    const float* dt_proj_b  = (const float*)d_in[6];
    const float* A_log      = (const float*)d_in[7];
    const float* Dp         = (const float*)d_in[8];
    const float* out_proj_w = (const float*)d_in[9];
    const float* norm_w     = (const float*)d_in[10];
    const float* fc_w       = (const float*)d_in[11];
    const float* fc_b       = (const float*)d_in[12];

    float* ws    = (float*)d_ws;
    float* z     = ws;                          // B*48*L = 786432
    float* xc    = z     + (size_t)B_ * ED * L_;
    float* delta = xc    + (size_t)B_ * ED * L_;
    float* y     = delta + (size_t)B_ * ED * L_;
    float* Bmat  = y     + (size_t)B_ * ED * L_;   // B*L*32 = 524288
    float* Cmat  = Bmat  + (size_t)B_ * L_ * NS;
    float* hA    = Cmat  + (size_t)B_ * L_ * NS;   // B*6*L = 98304
    float* hB    = hA    + (size_t)B_ * DM * L_;
    float* gA    = hB    + (size_t)B_ * DM * L_;   // B*ED*CH*NS = 786432
    float* gH    = gA    + (size_t)B_ * ED * CH * NS;
    // total ~6.3M floats = 25 MB

    const int nScanT = B_ * ED * CH * NS;          // 786432

    for (int i = 0; i < NLAYERS; ++i) {
        float* hout      = (i & 1) ? hB : hA;
        const float* hin = (i & 1) ? hA : hB;
        const float* ow  = (i == 0) ? out_proj_w
                                    : out_proj_w + (size_t)(i - 1) * DM * ED;
        k_fused_pre<<<B_ * CH, 256, 0, stream>>>(
            x, y, ow, hin, hout,
            in_proj_w + (size_t)i * 96 * DM, norm_w + (size_t)i * DM,
            conv_w + (size_t)i * ED * DCONV, conv_b + (size_t)i * ED,
            x_proj_w + (size_t)i * 65 * ED,
            dt_proj_w + (size_t)i * ED, dt_proj_b + (size_t)i * ED,
            A_log + (size_t)i * ED * NS,
            z, xc, delta, Bmat, Cmat, gA, gH, i);
        k_scan<<<(nScanT + 255) / 256, 256, 0, stream>>>(
            delta, xc, Bmat, Cmat, z,
            A_log + (size_t)i * ED * NS, Dp + (size_t)i * ED,
            gA, gH, y, (i == NLAYERS - 1) ? 1 : 0);
    }
    k_cls<<<1, 64, 0, stream>>>(y, fc_w, fc_b, (float*)d_out);
}